// Round 8
// baseline (446.489 us; speedup 1.0000x reference)
//
#include <hip/hip_runtime.h>
#include <hip/hip_bf16.h>

// StructureBuilder: masked patch-correlation attention. FP32 I/O, f16 internal.
//   prep:     conv1x1+inorm+relu -> q_act/k_act f16 images; vbar = tap-mean of V
//   build_kp: materialize K patch bank, row stride 168 (tiles = 1344 contiguous 16B chunks)
//   attn:     flash attention, key-split x2; Bk prefetched into REGISTERS right after
//             the start barrier (lands during compute), committed to LDS after the
//             end barrier -> barriers wait on lgkm only, global latency hidden.
//             Row-sums via ones-MFMA (no sum shuffles). NO launch_bounds VGPR cap
//             (round-6 lesson: forced cap -> 640 MB of spill traffic).
//   combine:  flash-merge halves + head-mean -> att
//   out:      Wo conv + inorm + relu -> fp32

#define LL 4096          // H*W
#define CC 64            // channels
#define AA 128           // attention channels
#define NH_ 8            // heads
#define KSTR 168         // kp row stride (f16): 144 data + pad; 21 x 8 halves
#define VSTR 72          // LDS row stride for Vt/Pb (9 x 16B)

typedef _Float16 half8 __attribute__((ext_vector_type(8)));
typedef float floatx4 __attribute__((ext_vector_type(4)));

// ---------------- K1: conv1x1 + inorm + relu -> activation images; vbar ----------------
__global__ __launch_bounds__(256) void prep_kernel(
    const float* __restrict__ feat,
    const float* __restrict__ masks,
    const float* __restrict__ Wq, const float* __restrict__ bq,
    const float* __restrict__ Wk, const float* __restrict__ bk,
    _Float16* __restrict__ q_act, _Float16* __restrict__ k_act,
    _Float16* __restrict__ vb)
{
    const int tid = threadIdx.x;
    const int b = blockIdx.x;
    __shared__ float sW[CC];
    __shared__ float sm[8];

    if (b >= 2 * AA) {
        // vbar[c][l] = (1/9) sum_taps f_unmasked[c, l + shift_t]  (OOB = 0)
        int c = b - 2 * AA;
        for (int p = 0; p < 16; ++p) {
            int l = p * 256 + tid;
            int y = l >> 6, x = l & 63;
            float s = 0.f;
            for (int ty = 0; ty < 3; ++ty) {
                int yy = y + 2 * (ty - 1);
                if (yy < 0 || yy > 63) continue;
                for (int tx = 0; tx < 3; ++tx) {
                    int xx = x + 2 * (tx - 1);
                    if (xx < 0 || xx > 63) continue;
                    int ll = yy * 64 + xx;
                    float hole = masks[ll] > 0.5f ? 1.f : 0.f;
                    s += feat[c * LL + ll] * (1.f - hole);
                }
            }
            vb[c * LL + l] = (_Float16)(s * (1.f / 9.f));
        }
        return;
    }

    const int a = b & (AA - 1);
    const int sel = b >> 7;  // 0 = q (hole pixels), 1 = k (unmasked pixels)
    const float* Wrow = (sel ? Wk : Wq) + a * CC;
    const float bias = sel ? bk[a] : bq[a];
    if (tid < CC) sW[tid] = Wrow[tid];
    __syncthreads();

    // conv: c-outer, pixel-inner (1 LDS read per 16 FMAs, 16-wide load ILP)
    float acc[16];
#pragma unroll
    for (int p = 0; p < 16; ++p) acc[p] = 0.f;
    for (int c = 0; c < CC; ++c) {
        float wc = sW[c];
        const float* fr = feat + (size_t)c * LL + tid;
#pragma unroll
        for (int p = 0; p < 16; ++p) acc[p] += wc * fr[p * 256];
    }

    float vals[16];
    float s1 = 0.f, s2 = 0.f;
#pragma unroll
    for (int p = 0; p < 16; ++p) {
        int l = p * 256 + tid;
        float hole = masks[l] > 0.5f ? 1.f : 0.f;
        float mf = sel ? (1.f - hole) : hole;
        float v = acc[p] * mf + bias;
        vals[p] = v; s1 += v; s2 += v * v;
    }
    for (int off = 32; off; off >>= 1) {
        s1 += __shfl_down(s1, off, 64);
        s2 += __shfl_down(s2, off, 64);
    }
    int wv = tid >> 6, ln = tid & 63;
    if (ln == 0) { sm[wv * 2] = s1; sm[wv * 2 + 1] = s2; }
    __syncthreads();
    s1 = sm[0] + sm[2] + sm[4] + sm[6];
    s2 = sm[1] + sm[3] + sm[5] + sm[7];
    float mu = s1 * (1.f / LL);
    float inv = rsqrtf(s2 * (1.f / LL) - mu * mu + 1e-5f);

    _Float16* act = (sel ? k_act : q_act) + (size_t)a * LL;
#pragma unroll
    for (int p = 0; p < 16; ++p) {
        int l = p * 256 + tid;
        float v = (vals[p] - mu) * inv;
        act[l] = (_Float16)(v > 0.f ? v : 0.f);
    }
}

// ---------------- K2: materialize K patch bank kp[n][l][KSTR] ----------------
__global__ __launch_bounds__(256) void build_kp(
    const _Float16* __restrict__ k_act, _Float16* __restrict__ kp)
{
    const int n = blockIdx.x, y = blockIdx.y;
    const int tid = threadIdx.x;
    const _Float16* ka = k_act + (size_t)n * 16 * LL;
    _Float16* base = kp + ((size_t)n * LL + y * 64) * KSTR;
#pragma unroll
    for (int i = 0; i < 6; ++i) {
        int idx = tid + i * 256;          // half8 chunk index within tile
        if (idx >= 64 * 21) break;
        int x = idx / 21, c21 = idx - x * 21;
        half8 v8;
#pragma unroll
        for (int j = 0; j < 8; ++j) {
            int d = c21 * 8 + j;
            _Float16 v = (_Float16)0.f;
            if (d < 144) {
                int ah = d / 9, t = d - ah * 9;
                int ty = t / 3, tx = t - ty * 3;
                int yy = y + 2 * (ty - 1);
                int xx = x + 2 * (tx - 1);
                if (yy >= 0 && yy <= 63 && xx >= 0 && xx <= 63)
                    v = ka[ah * LL + yy * 64 + xx];
            }
            v8[j] = v;
        }
        *(half8*)(base + (size_t)idx * 8) = v8;   // rows are exactly 21 chunks
    }
}

// ---------------- K3: flash attention, key-split x2 ----------------
// grid = (8 heads, 64 q-row tiles, 2 key halves); 256 threads (4 waves).
// LDS 39,936 B; register prefetch of the next Bk/Vt tile each iteration.
__global__ __launch_bounds__(256) void attn_kernel(
    const _Float16* __restrict__ q_act, const _Float16* __restrict__ kp,
    const _Float16* __restrict__ vb,
    _Float16* __restrict__ Opart, float* __restrict__ ml)
{
    const int n = blockIdx.x, qt = blockIdx.y, h = blockIdx.z;
    const int i0 = qt * 64;
    const int jt0 = h * 32;
    const int tid = threadIdx.x;
    const int w = tid >> 6, lane = tid & 63;
    const int l15 = lane & 15, quad = lane >> 4;

    __shared__ __align__(16) _Float16 Bk[64 * KSTR];    // 21504 B
    __shared__ __align__(16) _Float16 Vt[64 * VSTR];    //  9216 B
    __shared__ __align__(16) _Float16 Pb[4][16 * VSTR]; //  9216 B

    const _Float16* kpn = kp + (size_t)n * LL * KSTR;
    const uint4* vbu = (const uint4*)vb;

    const int vc0 = tid >> 3, ve0 = tid & 7;
    const int vc1 = (tid + 256) >> 3, ve1 = tid & 7;

    // A-fragments: query pixel (y=qt, x=w*16+l15), d-slice ks*32 + quad*8 (+j)
    half8 afrag[5];
    {
        const _Float16* qa = q_act + (size_t)n * 16 * LL;
        const int x = w * 16 + l15;
#pragma unroll
        for (int ks = 0; ks < 5; ++ks) {
#pragma unroll
            for (int j = 0; j < 8; ++j) {
                int d = ks * 32 + quad * 8 + j;
                _Float16 v = (_Float16)0.f;
                if (d < 144) {
                    int ah = d / 9, t = d - ah * 9;
                    int ty = t / 3, tx = t - ty * 3;
                    int yy = qt + 2 * (ty - 1);
                    int xx = x + 2 * (tx - 1);
                    if (yy >= 0 && yy <= 63 && xx >= 0 && xx <= 63)
                        v = qa[ah * LL + yy * 64 + xx];
                }
                afrag[ks][j] = v;
            }
        }
    }

    half8 ones;
#pragma unroll
    for (int j = 0; j < 8; ++j) ones[j] = (_Float16)1.f;

    floatx4 accO[4];
    floatx4 accL = (floatx4){0.f, 0.f, 0.f, 0.f};
    float mrow[4];
#pragma unroll
    for (int i = 0; i < 4; ++i) {
        accO[i] = (floatx4){0.f, 0.f, 0.f, 0.f};
        mrow[i] = -1e30f;
    }

    {   // prologue: stage tile jt0 directly (regs -> LDS)
        const uint4* src = (const uint4*)(kpn + (size_t)jt0 * 64 * KSTR);
        uint4* bd = (uint4*)Bk;
#pragma unroll
        for (int i = 0; i < 5; ++i) bd[tid + i * 256] = src[tid + i * 256];
        if (tid < 64) bd[tid + 1280] = src[tid + 1280];
        uint4* vd = (uint4*)Vt;
        vd[vc0 * 9 + ve0] = vbu[vc0 * (LL / 8) + jt0 * 8 + ve0];
        vd[vc1 * 9 + ve1] = vbu[vc1 * (LL / 8) + jt0 * 8 + ve1];
    }

    uint4 breg[6], vreg[2];
    for (int it = 0; it < 32; ++it) {
        __syncthreads();  // staged tile visible (lgkm-only wait)

        // issue global prefetch of tile it+1 NOW; it lands during compute
        if (it < 31) {
            const int jn = jt0 + it + 1;
            const uint4* src = (const uint4*)(kpn + (size_t)jn * 64 * KSTR);
#pragma unroll
            for (int i = 0; i < 5; ++i) breg[i] = src[tid + i * 256];
            if (tid < 64) breg[5] = src[tid + 1280];
            vreg[0] = vbu[vc0 * (LL / 8) + jn * 8 + ve0];
            vreg[1] = vbu[vc1 * (LL / 8) + jn * 8 + ve1];
        }

        // S tile: wave's 16 query pixels x 64 keys, K = 160 (tail zero)
        floatx4 accS[4];
#pragma unroll
        for (int i = 0; i < 4; ++i) accS[i] = (floatx4){0.f, 0.f, 0.f, 0.f};
        for (int ks = 0; ks < 5; ++ks) {
#pragma unroll
            for (int nt = 0; nt < 4; ++nt) {
                half8 bfr = *(const half8*)(Bk + (nt * 16 + l15) * KSTR + ks * 32 + quad * 8);
                accS[nt] = __builtin_amdgcn_mfma_f32_16x16x32_f16(afrag[ks], bfr, accS[nt], 0, 0, 0);
            }
        }

        // online softmax (max only; row-sum comes from the ones-MFMA below)
#pragma unroll
        for (int r = 0; r < 4; ++r) {
            float tm = fmaxf(fmaxf(accS[0][r], accS[1][r]), fmaxf(accS[2][r], accS[3][r]));
#pragma unroll
            for (int off = 8; off; off >>= 1) tm = fmaxf(tm, __shfl_xor(tm, off, 16));
            float mn = fmaxf(mrow[r], tm);
            float alpha = __expf(mrow[r] - mn);
            mrow[r] = mn;
#pragma unroll
            for (int nt = 0; nt < 4; ++nt) {
                accS[nt][r] = __expf(accS[nt][r] - mn);
                accO[nt][r] *= alpha;
            }
            accL[r] *= alpha;
        }

        // P: C-layout -> A-layout via per-wave LDS buffer, XOR-swizzled
        _Float16* pw = Pb[w];
#pragma unroll
        for (int nt = 0; nt < 4; ++nt)
#pragma unroll
            for (int r = 0; r < 4; ++r)
                pw[(quad * 4 + r) * VSTR + ((nt ^ quad) << 4) + l15] = (_Float16)accS[nt][r];

        // O += P @ Vt^T ; L += P @ 1  (K = 64 keys)
#pragma unroll
        for (int ks = 0; ks < 2; ++ks) {
            int kb = ks * 2 + (quad >> 1);
            half8 afr = *(const half8*)(pw + l15 * VSTR + ((kb ^ (l15 >> 2)) << 4) + (quad & 1) * 8);
            accL = __builtin_amdgcn_mfma_f32_16x16x32_f16(afr, ones, accL, 0, 0, 0);
#pragma unroll
            for (int nt = 0; nt < 4; ++nt) {
                half8 bfr = *(const half8*)(Vt + (nt * 16 + l15) * VSTR + ks * 32 + quad * 8);
                accO[nt] = __builtin_amdgcn_mfma_f32_16x16x32_f16(afr, bfr, accO[nt], 0, 0, 0);
            }
        }

        __syncthreads();  // all waves done reading Bk/Vt
        if (it < 31) {    // commit prefetched tile: fast ds_writes only
            uint4* bd = (uint4*)Bk;
#pragma unroll
            for (int i = 0; i < 5; ++i) bd[tid + i * 256] = breg[i];
            if (tid < 64) bd[tid + 1280] = breg[5];
            uint4* vd = (uint4*)Vt;
            vd[vc0 * 9 + ve0] = vreg[0];
            vd[vc1 * 9 + ve1] = vreg[1];
        }
    }

    // epilogue: normalized partial (f16) + (m,l) per q-row
    _Float16* op = Opart + ((size_t)(n * 2 + h) * LL + i0 + w * 16) * CC;
#pragma unroll
    for (int r = 0; r < 4; ++r) {
        float invl = 1.f / accL[r];
        int row = quad * 4 + r;
#pragma unroll
        for (int nt = 0; nt < 4; ++nt)
            op[row * CC + nt * 16 + l15] = (_Float16)(accO[nt][r] * invl);
        if (l15 == 0) {
            float* mlp = ml + ((size_t)n * LL + i0 + w * 16 + row) * 4;
            mlp[2 * h] = mrow[r];
            mlp[2 * h + 1] = accL[r];
        }
    }
}

// ---------------- K4: flash-merge halves + head-mean ----------------
__global__ __launch_bounds__(256) void combine_kernel(
    const _Float16* __restrict__ Opart, const float* __restrict__ ml,
    float* __restrict__ att)
{
    int t = blockIdx.x * 256 + threadIdx.x;   // 0 .. LL*CC-1
    int l = t >> 6, c = t & 63;
    float s = 0.f;
#pragma unroll
    for (int n = 0; n < NH_; ++n) {
        const float* mlp = ml + ((size_t)n * LL + l) * 4;
        float m0 = mlp[0], l0 = mlp[1], m1 = mlp[2], l1 = mlp[3];
        float M = fmaxf(m0, m1);
        float w0 = l0 * __expf(m0 - M);
        float w1 = l1 * __expf(m1 - M);
        float o0 = (float)Opart[((size_t)(2 * n) * LL + l) * CC + c];
        float o1 = (float)Opart[((size_t)(2 * n + 1) * LL + l) * CC + c];
        s += (w0 * o0 + w1 * o1) / (w0 + w1);
    }
    att[t] = s * 0.125f;
}

// ---------------- K5: Wo conv + inorm + relu ----------------
__global__ __launch_bounds__(256) void out_kernel(
    const float* __restrict__ att,
    const float* __restrict__ Wo, const float* __restrict__ bo,
    float* __restrict__ out)
{
    const int o = blockIdx.x;
    const int tid = threadIdx.x;
    __shared__ float sW[CC];
    __shared__ float sm[8];
    if (tid < CC) sW[tid] = Wo[o * CC + tid];
    __syncthreads();
    const float bias = bo[o];

    float vals[16], s1 = 0.f, s2 = 0.f;
    for (int p = 0; p < 16; ++p) {
        int l = p * 256 + tid;
        const float4* arow = (const float4*)(att + (size_t)l * CC);
        float acc = bias;
#pragma unroll
        for (int c4 = 0; c4 < 16; ++c4) {
            float4 a4 = arow[c4];
            acc += sW[c4 * 4] * a4.x + sW[c4 * 4 + 1] * a4.y +
                   sW[c4 * 4 + 2] * a4.z + sW[c4 * 4 + 3] * a4.w;
        }
        vals[p] = acc; s1 += acc; s2 += acc * acc;
    }
    for (int off = 32; off; off >>= 1) {
        s1 += __shfl_down(s1, off, 64);
        s2 += __shfl_down(s2, off, 64);
    }
    int wv = tid >> 6, ln = tid & 63;
    if (ln == 0) { sm[wv * 2] = s1; sm[wv * 2 + 1] = s2; }
    __syncthreads();
    s1 = sm[0] + sm[2] + sm[4] + sm[6];
    s2 = sm[1] + sm[3] + sm[5] + sm[7];
    float mu = s1 * (1.f / LL);
    float inv = rsqrtf(s2 * (1.f / LL) - mu * mu + 1e-5f);
    for (int p = 0; p < 16; ++p) {
        int l = p * 256 + tid;
        float v = (vals[p] - mu) * inv;
        out[(size_t)o * LL + l] = v > 0.f ? v : 0.f;
    }
}

extern "C" void kernel_launch(void* const* d_in, const int* in_sizes, int n_in,
                              void* d_out, int out_size, void* d_ws, size_t ws_size,
                              hipStream_t stream) {
    const float* feat  = (const float*)d_in[0];
    const float* masks = (const float*)d_in[1];
    const float* Wq    = (const float*)d_in[2];
    const float* bq    = (const float*)d_in[3];
    const float* Wk    = (const float*)d_in[4];
    const float* bk    = (const float*)d_in[5];
    const float* Wo    = (const float*)d_in[6];
    const float* bo    = (const float*)d_in[7];
    float* out = (float*)d_out;

    char* ws = (char*)d_ws;
    // layout (bytes) — total 23,592,960 (~22.5 MB):
    //   q_act f16 [128][4096]       @ 0          (1,048,576)
    //   k_act f16 [128][4096]       @ 1,048,576  (1,048,576)
    //   vb    f16 [64][4096]        @ 2,097,152  (  524,288)
    //   att   f32 [4096][64]        @ 2,621,440  (1,048,576)
    //   kp    f16 [8][4096][168]    @ 3,670,016  (11,010,048)
    //   Opart f16 [16][4096][64]    @ 14,680,064 (8,388,608)
    //   ml    f32 [8][4096][4]      @ 23,068,672 (  524,288)
    _Float16* q_act = (_Float16*)ws;
    _Float16* k_act = (_Float16*)(ws + 1048576);
    _Float16* vb    = (_Float16*)(ws + 2097152);
    float*    att   = (float*)(ws + 2621440);
    _Float16* kp    = (_Float16*)(ws + 3670016);
    _Float16* Opart = (_Float16*)(ws + 14680064);
    float*    ml    = (float*)(ws + 23068672);

    prep_kernel<<<2 * AA + CC, 256, 0, stream>>>(feat, masks, Wq, bq, Wk, bk,
                                                 q_act, k_act, vb);
    dim3 gb(NH_, 64);
    build_kp<<<gb, 256, 0, stream>>>(k_act, kp);
    dim3 g(NH_, 64, 2);
    attn_kernel<<<g, 256, 0, stream>>>(q_act, kp, vb, Opart, ml);
    combine_kernel<<<LL * CC / 256, 256, 0, stream>>>(Opart, ml, att);
    out_kernel<<<CC, 256, 0, stream>>>(att, Wo, bo, out);
}

// Round 9
// 322.296 us; speedup vs baseline: 1.3853x; 1.3853x over previous
//
#include <hip/hip_runtime.h>
#include <hip/hip_bf16.h>

// StructureBuilder: masked patch-correlation attention. FP32 I/O, f16 internal.
//   prep:     conv1x1+inorm+relu -> q_act/k_act f16 images; vbar = tap-mean of V
//   build_kp: materialize K patch bank, row stride 168 (tiles = 1344 contiguous 16B chunks)
//   attn:     flash attention, key-split x2. Bk double-buffered via async
//             global_load_lds issued right after the single per-iter barrier.
//             PV computes O^T = V @ P: V fragments load straight from global (L2-hot)
//             into the MFMA A-slot; P (LDS, XOR-swizzled) feeds the B-slot.
//             NO register staging of K tiles (rounds 6/8 lesson: allocator spills it).
//   combine:  flash-merge halves + head-mean -> att
//   out:      Wo conv + inorm + relu -> fp32

#define LL 4096          // H*W
#define CC 64            // channels
#define AA 128           // attention channels
#define NH_ 8            // heads
#define KSTR 168         // kp row stride (f16): 144 data + pad; 21 x 8 halves
#define VSTR 72          // LDS row stride for Pb (9 x 16B)

typedef _Float16 half8 __attribute__((ext_vector_type(8)));
typedef _Float16 half4 __attribute__((ext_vector_type(4)));
typedef float floatx4 __attribute__((ext_vector_type(4)));

// ---------------- K1: conv1x1 + inorm + relu -> activation images; vbar ----------------
__global__ __launch_bounds__(256) void prep_kernel(
    const float* __restrict__ feat,
    const float* __restrict__ masks,
    const float* __restrict__ Wq, const float* __restrict__ bq,
    const float* __restrict__ Wk, const float* __restrict__ bk,
    _Float16* __restrict__ q_act, _Float16* __restrict__ k_act,
    _Float16* __restrict__ vb)
{
    const int tid = threadIdx.x;
    const int b = blockIdx.x;
    __shared__ float sW[CC];
    __shared__ float sm[8];

    if (b >= 2 * AA) {
        // vbar[c][l] = (1/9) sum_taps f_unmasked[c, l + shift_t]  (OOB = 0)
        int c = b - 2 * AA;
        for (int p = 0; p < 16; ++p) {
            int l = p * 256 + tid;
            int y = l >> 6, x = l & 63;
            float s = 0.f;
            for (int ty = 0; ty < 3; ++ty) {
                int yy = y + 2 * (ty - 1);
                if (yy < 0 || yy > 63) continue;
                for (int tx = 0; tx < 3; ++tx) {
                    int xx = x + 2 * (tx - 1);
                    if (xx < 0 || xx > 63) continue;
                    int ll = yy * 64 + xx;
                    float hole = masks[ll] > 0.5f ? 1.f : 0.f;
                    s += feat[c * LL + ll] * (1.f - hole);
                }
            }
            vb[c * LL + l] = (_Float16)(s * (1.f / 9.f));
        }
        return;
    }

    const int a = b & (AA - 1);
    const int sel = b >> 7;  // 0 = q (hole pixels), 1 = k (unmasked pixels)
    const float* Wrow = (sel ? Wk : Wq) + a * CC;
    const float bias = sel ? bk[a] : bq[a];
    if (tid < CC) sW[tid] = Wrow[tid];
    __syncthreads();

    // conv: c-outer, pixel-inner (1 LDS read per 16 FMAs, 16-wide load ILP)
    float acc[16];
#pragma unroll
    for (int p = 0; p < 16; ++p) acc[p] = 0.f;
    for (int c = 0; c < CC; ++c) {
        float wc = sW[c];
        const float* fr = feat + (size_t)c * LL + tid;
#pragma unroll
        for (int p = 0; p < 16; ++p) acc[p] += wc * fr[p * 256];
    }

    float vals[16];
    float s1 = 0.f, s2 = 0.f;
#pragma unroll
    for (int p = 0; p < 16; ++p) {
        int l = p * 256 + tid;
        float hole = masks[l] > 0.5f ? 1.f : 0.f;
        float mf = sel ? (1.f - hole) : hole;
        float v = acc[p] * mf + bias;
        vals[p] = v; s1 += v; s2 += v * v;
    }
    for (int off = 32; off; off >>= 1) {
        s1 += __shfl_down(s1, off, 64);
        s2 += __shfl_down(s2, off, 64);
    }
    int wv = tid >> 6, ln = tid & 63;
    if (ln == 0) { sm[wv * 2] = s1; sm[wv * 2 + 1] = s2; }
    __syncthreads();
    s1 = sm[0] + sm[2] + sm[4] + sm[6];
    s2 = sm[1] + sm[3] + sm[5] + sm[7];
    float mu = s1 * (1.f / LL);
    float inv = rsqrtf(s2 * (1.f / LL) - mu * mu + 1e-5f);

    _Float16* act = (sel ? k_act : q_act) + (size_t)a * LL;
#pragma unroll
    for (int p = 0; p < 16; ++p) {
        int l = p * 256 + tid;
        float v = (vals[p] - mu) * inv;
        act[l] = (_Float16)(v > 0.f ? v : 0.f);
    }
}

// ---------------- K2: materialize K patch bank kp[n][l][KSTR] ----------------
__global__ __launch_bounds__(256) void build_kp(
    const _Float16* __restrict__ k_act, _Float16* __restrict__ kp)
{
    const int n = blockIdx.x, y = blockIdx.y;
    const int tid = threadIdx.x;
    const _Float16* ka = k_act + (size_t)n * 16 * LL;
    _Float16* base = kp + ((size_t)n * LL + y * 64) * KSTR;
#pragma unroll
    for (int i = 0; i < 6; ++i) {
        int idx = tid + i * 256;          // half8 chunk index within tile
        if (idx >= 64 * 21) break;
        int x = idx / 21, c21 = idx - x * 21;
        half8 v8;
#pragma unroll
        for (int j = 0; j < 8; ++j) {
            int d = c21 * 8 + j;
            _Float16 v = (_Float16)0.f;
            if (d < 144) {
                int ah = d / 9, t = d - ah * 9;
                int ty = t / 3, tx = t - ty * 3;
                int yy = y + 2 * (ty - 1);
                int xx = x + 2 * (tx - 1);
                if (yy >= 0 && yy <= 63 && xx >= 0 && xx <= 63)
                    v = ka[ah * LL + yy * 64 + xx];
            }
            v8[j] = v;
        }
        *(half8*)(base + (size_t)idx * 8) = v8;   // rows are exactly 21 chunks
    }
}

// ---------------- K3: flash attention, key-split x2 ----------------
// grid = (8 heads, 64 q-row tiles, 2 key halves); 256 threads (4 waves).
// LDS 52,224 B (Bk x2 + Pb) -> 3 blocks/CU.
__global__ __launch_bounds__(256) void attn_kernel(
    const _Float16* __restrict__ q_act, const _Float16* __restrict__ kp,
    const _Float16* __restrict__ vb,
    _Float16* __restrict__ Opart, float* __restrict__ ml)
{
    const int n = blockIdx.x, qt = blockIdx.y, h = blockIdx.z;
    const int i0 = qt * 64;
    const int jt0 = h * 32;
    const int tid = threadIdx.x;
    const int w = tid >> 6, lane = tid & 63;
    const int l15 = lane & 15, quad = lane >> 4;

    __shared__ __align__(16) _Float16 BkD[2][64 * KSTR];  // 2 x 21504 B
    __shared__ __align__(16) _Float16 Pb[4][16 * VSTR];   //      9216 B

    const _Float16* kpn = kp + (size_t)n * LL * KSTR;

    // async DMA: tile jt -> BkD[buf]. 21 chunks of 1024B; wave w takes chunks w, w+4, ...
    auto issue_bk = [&](int jt, int buf) {
        const char* tile = (const char*)(kpn + (size_t)jt * 64 * KSTR) + (lane << 4);
        _Float16* dst = BkD[buf];
        for (int c = w; c < 21; c += 4) {
            __builtin_amdgcn_global_load_lds(
                (const __attribute__((address_space(1))) void*)(tile + c * 1024),
                (__attribute__((address_space(3))) void*)(dst + c * 512),
                16, 0, 0);
        }
    };

    // A-fragments (Q): query pixel (y=qt, x=w*16+l15), d-slice ks*32 + quad*8 (+j)
    half8 afrag[5];
    {
        const _Float16* qa = q_act + (size_t)n * 16 * LL;
        const int x = w * 16 + l15;
#pragma unroll
        for (int ks = 0; ks < 5; ++ks) {
#pragma unroll
            for (int j = 0; j < 8; ++j) {
                int d = ks * 32 + quad * 8 + j;
                _Float16 v = (_Float16)0.f;
                if (d < 144) {
                    int ah = d / 9, t = d - ah * 9;
                    int ty = t / 3, tx = t - ty * 3;
                    int yy = qt + 2 * (ty - 1);
                    int xx = x + 2 * (tx - 1);
                    if (yy >= 0 && yy <= 63 && xx >= 0 && xx <= 63)
                        v = qa[ah * LL + yy * 64 + xx];
                }
                afrag[ks][j] = v;
            }
        }
    }

    floatx4 accO[4];          // O^T: row ch = mt*16+quad*4+r, col q = l15
    float mrow[4], lrow[4];   // softmax state for S rows quad*4+r (wave-local)
#pragma unroll
    for (int i = 0; i < 4; ++i) {
        accO[i] = (floatx4){0.f, 0.f, 0.f, 0.f};
        mrow[i] = -1e30f; lrow[i] = 0.f;
    }

    issue_bk(jt0, 0);  // prologue DMA, in flight

    for (int it = 0; it < 32; ++it) {
        const int jt = jt0 + it;
        const _Float16* Bk = BkD[it & 1];
        __syncthreads();  // DMA into current buf drained (vmcnt0); prev buf's readers done
        if (it < 31) issue_bk(jt + 1, (it & 1) ^ 1);  // lands during this iter's compute

        // S tile: wave's 16 query pixels x 64 keys, K = 160 (tail zero)
        floatx4 accS[4];
#pragma unroll
        for (int i = 0; i < 4; ++i) accS[i] = (floatx4){0.f, 0.f, 0.f, 0.f};
        for (int ks = 0; ks < 5; ++ks) {
#pragma unroll
            for (int nt = 0; nt < 4; ++nt) {
                half8 bfr = *(const half8*)(Bk + (nt * 16 + l15) * KSTR + ks * 32 + quad * 8);
                accS[nt] = __builtin_amdgcn_mfma_f32_16x16x32_f16(afrag[ks], bfr, accS[nt], 0, 0, 0);
            }
        }

        // V A-fragments for this tile straight from global (L2-hot); latency
        // covered by the softmax below + co-resident waves.
        half8 vf0[4], vf1[4];
#pragma unroll
        for (int mt = 0; mt < 4; ++mt)
            vf0[mt] = *(const half8*)(vb + (size_t)(mt * 16 + l15) * LL + jt * 64 + quad * 8);
#pragma unroll
        for (int mt = 0; mt < 4; ++mt)
            vf1[mt] = *(const half8*)(vb + (size_t)(mt * 16 + l15) * LL + jt * 64 + 32 + quad * 8);

        // online softmax; S D-layout: row = quad*4+r, col = l15
        float alpha4[4];
#pragma unroll
        for (int r = 0; r < 4; ++r) {
            float tm = fmaxf(fmaxf(accS[0][r], accS[1][r]), fmaxf(accS[2][r], accS[3][r]));
#pragma unroll
            for (int off = 8; off; off >>= 1) tm = fmaxf(tm, __shfl_xor(tm, off, 16));
            float mn = fmaxf(mrow[r], tm);
            alpha4[r] = __expf(mrow[r] - mn);
            mrow[r] = mn;
            float rs = 0.f;
#pragma unroll
            for (int nt = 0; nt < 4; ++nt) {
                float pv = __expf(accS[nt][r] - mn);
                accS[nt][r] = pv;
                rs += pv;
            }
#pragma unroll
            for (int off = 8; off; off >>= 1) rs += __shfl_xor(rs, off, 16);
            lrow[r] = lrow[r] * alpha4[r] + rs;
        }
        // broadcast alpha of row q = l15 to this lane (accO cols are q = l15)
        {
            float av = (l15 & 2) ? ((l15 & 1) ? alpha4[3] : alpha4[2])
                                 : ((l15 & 1) ? alpha4[1] : alpha4[0]);
            float myal = __shfl(av, (l15 >> 2) * 16 + l15, 64);
#pragma unroll
            for (int mt = 0; mt < 4; ++mt) accO[mt] *= myal;
        }

        // P: C-layout -> LDS (XOR-swizzled), then read as MFMA B-operand
        _Float16* pw = Pb[w];
#pragma unroll
        for (int nt = 0; nt < 4; ++nt)
#pragma unroll
            for (int r = 0; r < 4; ++r)
                pw[(quad * 4 + r) * VSTR + ((nt ^ quad) << 4) + l15] = (_Float16)accS[nt][r];

        // O^T += V @ P  (A = V from global regs, B = P from Pb; K = 64 keys)
#pragma unroll
        for (int ks = 0; ks < 2; ++ks) {
            int kb = ks * 2 + (quad >> 1);
            half8 pfr = *(const half8*)(pw + l15 * VSTR + ((kb ^ (l15 >> 2)) << 4) + (quad & 1) * 8);
#pragma unroll
            for (int mt = 0; mt < 4; ++mt) {
                half8 vfr = ks ? vf1[mt] : vf0[mt];
                accO[mt] = __builtin_amdgcn_mfma_f32_16x16x32_f16(vfr, pfr, accO[mt], 0, 0, 0);
            }
        }
    }

    // epilogue: normalized partial (f16, O^T layout -> Opart[q][ch]) + (m,l) per q-row
    {
        float lv = (l15 & 2) ? ((l15 & 1) ? lrow[3] : lrow[2])
                             : ((l15 & 1) ? lrow[1] : lrow[0]);
        float myl = __shfl(lv, (l15 >> 2) * 16 + l15, 64);
        float invl = 1.f / myl;
        _Float16* op = Opart + ((size_t)(n * 2 + h) * LL + i0 + w * 16 + l15) * CC;
#pragma unroll
        for (int mt = 0; mt < 4; ++mt) {
            half4 pk;
#pragma unroll
            for (int r = 0; r < 4; ++r) pk[r] = (_Float16)(accO[mt][r] * invl);
            *(half4*)(op + mt * 16 + quad * 4) = pk;
        }
        if (l15 == 0) {
#pragma unroll
            for (int r = 0; r < 4; ++r) {
                float* mlp = ml + ((size_t)n * LL + i0 + w * 16 + quad * 4 + r) * 4;
                mlp[2 * h] = mrow[r];
                mlp[2 * h + 1] = lrow[r];
            }
        }
    }
}

// ---------------- K4: flash-merge halves + head-mean ----------------
__global__ __launch_bounds__(256) void combine_kernel(
    const _Float16* __restrict__ Opart, const float* __restrict__ ml,
    float* __restrict__ att)
{
    int t = blockIdx.x * 256 + threadIdx.x;   // 0 .. LL*CC-1
    int l = t >> 6, c = t & 63;
    float s = 0.f;
#pragma unroll
    for (int n = 0; n < NH_; ++n) {
        const float* mlp = ml + ((size_t)n * LL + l) * 4;
        float m0 = mlp[0], l0 = mlp[1], m1 = mlp[2], l1 = mlp[3];
        float M = fmaxf(m0, m1);
        float w0 = l0 * __expf(m0 - M);
        float w1 = l1 * __expf(m1 - M);
        float o0 = (float)Opart[((size_t)(2 * n) * LL + l) * CC + c];
        float o1 = (float)Opart[((size_t)(2 * n + 1) * LL + l) * CC + c];
        s += (w0 * o0 + w1 * o1) / (w0 + w1);
    }
    att[t] = s * 0.125f;
}

// ---------------- K5: Wo conv + inorm + relu ----------------
__global__ __launch_bounds__(256) void out_kernel(
    const float* __restrict__ att,
    const float* __restrict__ Wo, const float* __restrict__ bo,
    float* __restrict__ out)
{
    const int o = blockIdx.x;
    const int tid = threadIdx.x;
    __shared__ float sW[CC];
    __shared__ float sm[8];
    if (tid < CC) sW[tid] = Wo[o * CC + tid];
    __syncthreads();
    const float bias = bo[o];

    float vals[16], s1 = 0.f, s2 = 0.f;
    for (int p = 0; p < 16; ++p) {
        int l = p * 256 + tid;
        const float4* arow = (const float4*)(att + (size_t)l * CC);
        float acc = bias;
#pragma unroll
        for (int c4 = 0; c4 < 16; ++c4) {
            float4 a4 = arow[c4];
            acc += sW[c4 * 4] * a4.x + sW[c4 * 4 + 1] * a4.y +
                   sW[c4 * 4 + 2] * a4.z + sW[c4 * 4 + 3] * a4.w;
        }
        vals[p] = acc; s1 += acc; s2 += acc * acc;
    }
    for (int off = 32; off; off >>= 1) {
        s1 += __shfl_down(s1, off, 64);
        s2 += __shfl_down(s2, off, 64);
    }
    int wv = tid >> 6, ln = tid & 63;
    if (ln == 0) { sm[wv * 2] = s1; sm[wv * 2 + 1] = s2; }
    __syncthreads();
    s1 = sm[0] + sm[2] + sm[4] + sm[6];
    s2 = sm[1] + sm[3] + sm[5] + sm[7];
    float mu = s1 * (1.f / LL);
    float inv = rsqrtf(s2 * (1.f / LL) - mu * mu + 1e-5f);
    for (int p = 0; p < 16; ++p) {
        int l = p * 256 + tid;
        float v = (vals[p] - mu) * inv;
        out[(size_t)o * LL + l] = v > 0.f ? v : 0.f;
    }
}

extern "C" void kernel_launch(void* const* d_in, const int* in_sizes, int n_in,
                              void* d_out, int out_size, void* d_ws, size_t ws_size,
                              hipStream_t stream) {
    const float* feat  = (const float*)d_in[0];
    const float* masks = (const float*)d_in[1];
    const float* Wq    = (const float*)d_in[2];
    const float* bq    = (const float*)d_in[3];
    const float* Wk    = (const float*)d_in[4];
    const float* bk    = (const float*)d_in[5];
    const float* Wo    = (const float*)d_in[6];
    const float* bo    = (const float*)d_in[7];
    float* out = (float*)d_out;

    char* ws = (char*)d_ws;
    // layout (bytes) — total 23,592,960 (~22.5 MB):
    //   q_act f16 [128][4096]       @ 0          (1,048,576)
    //   k_act f16 [128][4096]       @ 1,048,576  (1,048,576)
    //   vb    f16 [64][4096]        @ 2,097,152  (  524,288)
    //   att   f32 [4096][64]        @ 2,621,440  (1,048,576)
    //   kp    f16 [8][4096][168]    @ 3,670,016  (11,010,048)
    //   Opart f16 [16][4096][64]    @ 14,680,064 (8,388,608)
    //   ml    f32 [8][4096][4]      @ 23,068,672 (  524,288)
    _Float16* q_act = (_Float16*)ws;
    _Float16* k_act = (_Float16*)(ws + 1048576);
    _Float16* vb    = (_Float16*)(ws + 2097152);
    float*    att   = (float*)(ws + 2621440);
    _Float16* kp    = (_Float16*)(ws + 3670016);
    _Float16* Opart = (_Float16*)(ws + 14680064);
    float*    ml    = (float*)(ws + 23068672);

    prep_kernel<<<2 * AA + CC, 256, 0, stream>>>(feat, masks, Wq, bq, Wk, bk,
                                                 q_act, k_act, vb);
    dim3 gb(NH_, 64);
    build_kp<<<gb, 256, 0, stream>>>(k_act, kp);
    dim3 g(NH_, 64, 2);
    attn_kernel<<<g, 256, 0, stream>>>(q_act, kp, vb, Opart, ml);
    combine_kernel<<<LL * CC / 256, 256, 0, stream>>>(Opart, ml, att);
    out_kernel<<<CC, 256, 0, stream>>>(att, Wo, bo, out);
}

// Round 12
// 301.523 us; speedup vs baseline: 1.4808x; 1.0689x over previous
//
#include <hip/hip_runtime.h>
#include <hip/hip_bf16.h>

// StructureBuilder: masked patch-correlation attention. FP32 I/O, f16 internal.
// BISECTION BUILD: attn = verbatim round-9 kernel (256 thr, PASSING at 220us);
// prep vbar split + out_stats/out_final split kept (the other round-10 suspects).
//   prep:      conv1x1+inorm+relu -> q_act/k_act f16 images; vbar (4-way split)
//   build_kp:  materialize K patch bank, row stride 168
//   attn:      flash attention, key-split x2, double-buffered Bk via global_load_lds,
//              V fragments from global into MFMA A-slot (O^T = V@P)  [round-9 verbatim]
//   combine:   flash-merge halves + head-mean -> att (also zeroes inorm stats)
//   out_stats/out_final: Wo conv + inorm + relu, two-phase
// Workspace: 23,592,960 B total; y/stats alias the kp region (dead after attn).

#define LL 4096          // H*W
#define CC 64            // channels
#define AA 128           // attention channels
#define NH_ 8            // heads
#define KSTR 168         // kp row stride (f16): 144 data + pad; 21 x 8 halves
#define VSTR 72          // LDS row stride for Pb (9 x 16B)

typedef _Float16 half8 __attribute__((ext_vector_type(8)));
typedef _Float16 half4 __attribute__((ext_vector_type(4)));
typedef float floatx4 __attribute__((ext_vector_type(4)));

// ---------------- K1: conv1x1 + inorm + relu -> activation images; vbar ----------------
// grid: [0,256) conv blocks (a,sel); [256,512) vbar blocks (c, px-chunk)
__global__ __launch_bounds__(256) void prep_kernel(
    const float* __restrict__ feat,
    const float* __restrict__ masks,
    const float* __restrict__ Wq, const float* __restrict__ bq,
    const float* __restrict__ Wk, const float* __restrict__ bk,
    _Float16* __restrict__ q_act, _Float16* __restrict__ k_act,
    _Float16* __restrict__ vb)
{
    const int tid = threadIdx.x;
    const int b = blockIdx.x;
    __shared__ float sW[CC];
    __shared__ float sm[8];

    if (b >= 2 * AA) {
        // vbar[c][l] = (1/9) sum_taps f_unmasked[c, l + shift_t]  (OOB = 0)
        int idx = b - 2 * AA;
        int c = idx >> 2, chunk = idx & 3;
        for (int p = 0; p < 4; ++p) {
            int l = chunk * 1024 + p * 256 + tid;
            int y = l >> 6, x = l & 63;
            float s = 0.f;
            for (int ty = 0; ty < 3; ++ty) {
                int yy = y + 2 * (ty - 1);
                if (yy < 0 || yy > 63) continue;
                for (int tx = 0; tx < 3; ++tx) {
                    int xx = x + 2 * (tx - 1);
                    if (xx < 0 || xx > 63) continue;
                    int ll = yy * 64 + xx;
                    float hole = masks[ll] > 0.5f ? 1.f : 0.f;
                    s += feat[c * LL + ll] * (1.f - hole);
                }
            }
            vb[c * LL + l] = (_Float16)(s * (1.f / 9.f));
        }
        return;
    }

    const int a = b & (AA - 1);
    const int sel = b >> 7;  // 0 = q (hole pixels), 1 = k (unmasked pixels)
    const float* Wrow = (sel ? Wk : Wq) + a * CC;
    const float bias = sel ? bk[a] : bq[a];
    if (tid < CC) sW[tid] = Wrow[tid];
    __syncthreads();

    float acc[16];
#pragma unroll
    for (int p = 0; p < 16; ++p) acc[p] = 0.f;
    for (int c = 0; c < CC; ++c) {
        float wc = sW[c];
        const float* fr = feat + (size_t)c * LL + tid;
#pragma unroll
        for (int p = 0; p < 16; ++p) acc[p] += wc * fr[p * 256];
    }

    float vals[16];
    float s1 = 0.f, s2 = 0.f;
#pragma unroll
    for (int p = 0; p < 16; ++p) {
        int l = p * 256 + tid;
        float hole = masks[l] > 0.5f ? 1.f : 0.f;
        float mf = sel ? (1.f - hole) : hole;
        float v = acc[p] * mf + bias;
        vals[p] = v; s1 += v; s2 += v * v;
    }
    for (int off = 32; off; off >>= 1) {
        s1 += __shfl_down(s1, off, 64);
        s2 += __shfl_down(s2, off, 64);
    }
    int wv = tid >> 6, ln = tid & 63;
    if (ln == 0) { sm[wv * 2] = s1; sm[wv * 2 + 1] = s2; }
    __syncthreads();
    s1 = sm[0] + sm[2] + sm[4] + sm[6];
    s2 = sm[1] + sm[3] + sm[5] + sm[7];
    float mu = s1 * (1.f / LL);
    float inv = rsqrtf(s2 * (1.f / LL) - mu * mu + 1e-5f);

    _Float16* act = (sel ? k_act : q_act) + (size_t)a * LL;
#pragma unroll
    for (int p = 0; p < 16; ++p) {
        int l = p * 256 + tid;
        float v = (vals[p] - mu) * inv;
        act[l] = (_Float16)(v > 0.f ? v : 0.f);
    }
}

// ---------------- K2: materialize K patch bank kp[n][l][KSTR] ----------------
__global__ __launch_bounds__(256) void build_kp(
    const _Float16* __restrict__ k_act, _Float16* __restrict__ kp)
{
    const int n = blockIdx.x, y = blockIdx.y;
    const int tid = threadIdx.x;
    const _Float16* ka = k_act + (size_t)n * 16 * LL;
    _Float16* base = kp + ((size_t)n * LL + y * 64) * KSTR;
#pragma unroll
    for (int i = 0; i < 6; ++i) {
        int idx = tid + i * 256;          // half8 chunk index within tile
        if (idx >= 64 * 21) break;
        int x = idx / 21, c21 = idx - x * 21;
        half8 v8;
#pragma unroll
        for (int j = 0; j < 8; ++j) {
            int d = c21 * 8 + j;
            _Float16 v = (_Float16)0.f;
            if (d < 144) {
                int ah = d / 9, t = d - ah * 9;
                int ty = t / 3, tx = t - ty * 3;
                int yy = y + 2 * (ty - 1);
                int xx = x + 2 * (tx - 1);
                if (yy >= 0 && yy <= 63 && xx >= 0 && xx <= 63)
                    v = ka[ah * LL + yy * 64 + xx];
            }
            v8[j] = v;
        }
        *(half8*)(base + (size_t)idx * 8) = v8;   // rows are exactly 21 chunks
    }
}

// ---------------- K3: flash attention, key-split x2 [ROUND-9 VERBATIM] ----------------
// grid = (8 heads, 64 q-row tiles, 2 key halves); 256 threads (4 waves).
// LDS 52,224 B (Bk x2 + Pb) -> 3 blocks/CU.
__global__ __launch_bounds__(256) void attn_kernel(
    const _Float16* __restrict__ q_act, const _Float16* __restrict__ kp,
    const _Float16* __restrict__ vb,
    _Float16* __restrict__ Opart, float* __restrict__ ml)
{
    const int n = blockIdx.x, qt = blockIdx.y, h = blockIdx.z;
    const int i0 = qt * 64;
    const int jt0 = h * 32;
    const int tid = threadIdx.x;
    const int w = tid >> 6, lane = tid & 63;
    const int l15 = lane & 15, quad = lane >> 4;

    __shared__ __align__(16) _Float16 BkD[2][64 * KSTR];  // 2 x 21504 B
    __shared__ __align__(16) _Float16 Pb[4][16 * VSTR];   //      9216 B

    const _Float16* kpn = kp + (size_t)n * LL * KSTR;

    auto issue_bk = [&](int jt, int buf) {
        const char* tile = (const char*)(kpn + (size_t)jt * 64 * KSTR) + (lane << 4);
        _Float16* dst = BkD[buf];
        for (int c = w; c < 21; c += 4) {
            __builtin_amdgcn_global_load_lds(
                (const __attribute__((address_space(1))) void*)(tile + c * 1024),
                (__attribute__((address_space(3))) void*)(dst + c * 512),
                16, 0, 0);
        }
    };

    half8 afrag[5];
    {
        const _Float16* qa = q_act + (size_t)n * 16 * LL;
        const int x = w * 16 + l15;
#pragma unroll
        for (int ks = 0; ks < 5; ++ks) {
#pragma unroll
            for (int j = 0; j < 8; ++j) {
                int d = ks * 32 + quad * 8 + j;
                _Float16 v = (_Float16)0.f;
                if (d < 144) {
                    int ah = d / 9, t = d - ah * 9;
                    int ty = t / 3, tx = t - ty * 3;
                    int yy = qt + 2 * (ty - 1);
                    int xx = x + 2 * (tx - 1);
                    if (yy >= 0 && yy <= 63 && xx >= 0 && xx <= 63)
                        v = qa[ah * LL + yy * 64 + xx];
                }
                afrag[ks][j] = v;
            }
        }
    }

    floatx4 accO[4];          // O^T: row ch = mt*16+quad*4+r, col q = l15
    float mrow[4], lrow[4];   // softmax state for S rows quad*4+r (wave-local)
#pragma unroll
    for (int i = 0; i < 4; ++i) {
        accO[i] = (floatx4){0.f, 0.f, 0.f, 0.f};
        mrow[i] = -1e30f; lrow[i] = 0.f;
    }

    issue_bk(jt0, 0);  // prologue DMA, in flight

    for (int it = 0; it < 32; ++it) {
        const int jt = jt0 + it;
        const _Float16* Bk = BkD[it & 1];
        __syncthreads();  // DMA into current buf drained; prev buf's readers done
        if (it < 31) issue_bk(jt + 1, (it & 1) ^ 1);  // lands during compute

        floatx4 accS[4];
#pragma unroll
        for (int i = 0; i < 4; ++i) accS[i] = (floatx4){0.f, 0.f, 0.f, 0.f};
        for (int ks = 0; ks < 5; ++ks) {
#pragma unroll
            for (int nt = 0; nt < 4; ++nt) {
                half8 bfr = *(const half8*)(Bk + (nt * 16 + l15) * KSTR + ks * 32 + quad * 8);
                accS[nt] = __builtin_amdgcn_mfma_f32_16x16x32_f16(afrag[ks], bfr, accS[nt], 0, 0, 0);
            }
        }

        half8 vf0[4], vf1[4];
#pragma unroll
        for (int mt = 0; mt < 4; ++mt)
            vf0[mt] = *(const half8*)(vb + (size_t)(mt * 16 + l15) * LL + jt * 64 + quad * 8);
#pragma unroll
        for (int mt = 0; mt < 4; ++mt)
            vf1[mt] = *(const half8*)(vb + (size_t)(mt * 16 + l15) * LL + jt * 64 + 32 + quad * 8);

        float alpha4[4];
#pragma unroll
        for (int r = 0; r < 4; ++r) {
            float tm = fmaxf(fmaxf(accS[0][r], accS[1][r]), fmaxf(accS[2][r], accS[3][r]));
#pragma unroll
            for (int off = 8; off; off >>= 1) tm = fmaxf(tm, __shfl_xor(tm, off, 16));
            float mn = fmaxf(mrow[r], tm);
            alpha4[r] = __expf(mrow[r] - mn);
            mrow[r] = mn;
            float rs = 0.f;
#pragma unroll
            for (int nt = 0; nt < 4; ++nt) {
                float pv = __expf(accS[nt][r] - mn);
                accS[nt][r] = pv;
                rs += pv;
            }
#pragma unroll
            for (int off = 8; off; off >>= 1) rs += __shfl_xor(rs, off, 16);
            lrow[r] = lrow[r] * alpha4[r] + rs;
        }
        {
            float av = (l15 & 2) ? ((l15 & 1) ? alpha4[3] : alpha4[2])
                                 : ((l15 & 1) ? alpha4[1] : alpha4[0]);
            float myal = __shfl(av, (l15 >> 2) * 16 + l15, 64);
#pragma unroll
            for (int mt = 0; mt < 4; ++mt) accO[mt] *= myal;
        }

        _Float16* pw = Pb[w];
#pragma unroll
        for (int nt = 0; nt < 4; ++nt)
#pragma unroll
            for (int r = 0; r < 4; ++r)
                pw[(quad * 4 + r) * VSTR + ((nt ^ quad) << 4) + l15] = (_Float16)accS[nt][r];

#pragma unroll
        for (int ks = 0; ks < 2; ++ks) {
            int kb = ks * 2 + (quad >> 1);
            half8 pfr = *(const half8*)(pw + l15 * VSTR + ((kb ^ (l15 >> 2)) << 4) + (quad & 1) * 8);
#pragma unroll
            for (int mt = 0; mt < 4; ++mt) {
                half8 vfr = ks ? vf1[mt] : vf0[mt];
                accO[mt] = __builtin_amdgcn_mfma_f32_16x16x32_f16(vfr, pfr, accO[mt], 0, 0, 0);
            }
        }
    }

    {
        float lv = (l15 & 2) ? ((l15 & 1) ? lrow[3] : lrow[2])
                             : ((l15 & 1) ? lrow[1] : lrow[0]);
        float myl = __shfl(lv, (l15 >> 2) * 16 + l15, 64);
        float invl = 1.f / myl;
        _Float16* op = Opart + ((size_t)(n * 2 + h) * LL + i0 + w * 16 + l15) * CC;
#pragma unroll
        for (int mt = 0; mt < 4; ++mt) {
            half4 pk;
#pragma unroll
            for (int r = 0; r < 4; ++r) pk[r] = (_Float16)(accO[mt][r] * invl);
            *(half4*)(op + mt * 16 + quad * 4) = pk;
        }
        if (l15 == 0) {
#pragma unroll
            for (int r = 0; r < 4; ++r) {
                float* mlp = ml + ((size_t)n * LL + i0 + w * 16 + quad * 4 + r) * 4;
                mlp[2 * h] = mrow[r];
                mlp[2 * h + 1] = lrow[r];
            }
        }
    }
}

// ---------------- K4: flash-merge halves + head-mean; zero inorm stats ----------------
__global__ __launch_bounds__(256) void combine_kernel(
    const _Float16* __restrict__ Opart, const float* __restrict__ ml,
    float* __restrict__ att, float* __restrict__ stats)
{
    if (blockIdx.x == 0 && threadIdx.x < 128) stats[threadIdx.x] = 0.f;

    int t = blockIdx.x * 256 + threadIdx.x;   // 0 .. LL*CC-1
    int l = t >> 6, c = t & 63;
    float s = 0.f;
#pragma unroll
    for (int n = 0; n < NH_; ++n) {
        const float* mlp = ml + ((size_t)n * LL + l) * 4;
        float m0 = mlp[0], l0 = mlp[1], m1 = mlp[2], l1 = mlp[3];
        float M = fmaxf(m0, m1);
        float w0 = l0 * __expf(m0 - M);
        float w1 = l1 * __expf(m1 - M);
        float o0 = (float)Opart[((size_t)(2 * n) * LL + l) * CC + c];
        float o1 = (float)Opart[((size_t)(2 * n + 1) * LL + l) * CC + c];
        s += (w0 * o0 + w1 * o1) / (w0 + w1);
    }
    att[t] = s * 0.125f;
}

// ---------------- K5a: Wo conv, partial inorm stats ----------------
__global__ __launch_bounds__(256) void out_stats(
    const float* __restrict__ att,
    const float* __restrict__ Wo, const float* __restrict__ bo,
    float* __restrict__ y, float* __restrict__ stats)
{
    const int o = blockIdx.x, chunk = blockIdx.y;
    const int tid = threadIdx.x;
    __shared__ float sW[CC];
    __shared__ float sm[8];
    if (tid < CC) sW[tid] = Wo[o * CC + tid];
    __syncthreads();
    const float bias = bo[o];

    float s1 = 0.f, s2 = 0.f;
#pragma unroll
    for (int p = 0; p < 4; ++p) {
        int l = chunk * 1024 + p * 256 + tid;
        const float4* arow = (const float4*)(att + (size_t)l * CC);
        float acc = bias;
#pragma unroll
        for (int c4 = 0; c4 < 16; ++c4) {
            float4 a4 = arow[c4];
            acc += sW[c4 * 4] * a4.x + sW[c4 * 4 + 1] * a4.y +
                   sW[c4 * 4 + 2] * a4.z + sW[c4 * 4 + 3] * a4.w;
        }
        y[(size_t)o * LL + l] = acc;
        s1 += acc; s2 += acc * acc;
    }
    for (int off = 32; off; off >>= 1) {
        s1 += __shfl_down(s1, off, 64);
        s2 += __shfl_down(s2, off, 64);
    }
    int wv = tid >> 6, ln = tid & 63;
    if (ln == 0) { sm[wv * 2] = s1; sm[wv * 2 + 1] = s2; }
    __syncthreads();
    if (tid == 0) {
        atomicAdd(stats + o * 2,     sm[0] + sm[2] + sm[4] + sm[6]);
        atomicAdd(stats + o * 2 + 1, sm[1] + sm[3] + sm[5] + sm[7]);
    }
}

// ---------------- K5b: finalize inorm + relu ----------------
__global__ __launch_bounds__(256) void out_final(
    const float* __restrict__ y, const float* __restrict__ stats,
    float* __restrict__ out)
{
    const int o = blockIdx.x, chunk = blockIdx.y;
    const int tid = threadIdx.x;
    float mu = stats[o * 2] * (1.f / LL);
    float inv = rsqrtf(stats[o * 2 + 1] * (1.f / LL) - mu * mu + 1e-5f);
#pragma unroll
    for (int p = 0; p < 4; ++p) {
        int l = chunk * 1024 + p * 256 + tid;
        float v = (y[(size_t)o * LL + l] - mu) * inv;
        out[(size_t)o * LL + l] = v > 0.f ? v : 0.f;
    }
}

extern "C" void kernel_launch(void* const* d_in, const int* in_sizes, int n_in,
                              void* d_out, int out_size, void* d_ws, size_t ws_size,
                              hipStream_t stream) {
    const float* feat  = (const float*)d_in[0];
    const float* masks = (const float*)d_in[1];
    const float* Wq    = (const float*)d_in[2];
    const float* bq    = (const float*)d_in[3];
    const float* Wk    = (const float*)d_in[4];
    const float* bk    = (const float*)d_in[5];
    const float* Wo    = (const float*)d_in[6];
    const float* bo    = (const float*)d_in[7];
    float* out = (float*)d_out;

    char* ws = (char*)d_ws;
    // layout (bytes) — total EXACTLY 23,592,960:
    //   q_act f16 [128][4096]       @ 0          (1,048,576)
    //   k_act f16 [128][4096]       @ 1,048,576  (1,048,576)
    //   vb    f16 [64][4096]        @ 2,097,152  (  524,288)
    //   att   f32 [4096][64]        @ 2,621,440  (1,048,576)
    //   kp    f16 [8][4096][168]    @ 3,670,016  (11,010,048)
    //     y     f32 [64][4096]      @ 3,670,016  -- ALIASES kp (dead after attn)
    //     stats f32 [128]           @ 4,718,592  -- ALIASES kp
    //   Opart f16 [16][4096][64]    @ 14,680,064 (8,388,608)
    //   ml    f32 [8][4096][4]      @ 23,068,672 (  524,288)
    _Float16* q_act = (_Float16*)ws;
    _Float16* k_act = (_Float16*)(ws + 1048576);
    _Float16* vb    = (_Float16*)(ws + 2097152);
    float*    att   = (float*)(ws + 2621440);
    _Float16* kp    = (_Float16*)(ws + 3670016);
    float*    y     = (float*)(ws + 3670016);
    float*    stats = (float*)(ws + 4718592);
    _Float16* Opart = (_Float16*)(ws + 14680064);
    float*    ml    = (float*)(ws + 23068672);

    prep_kernel<<<2 * AA + 4 * CC, 256, 0, stream>>>(feat, masks, Wq, bq, Wk, bk,
                                                     q_act, k_act, vb);
    dim3 gb(NH_, 64);
    build_kp<<<gb, 256, 0, stream>>>(k_act, kp);
    dim3 g(NH_, 64, 2);
    attn_kernel<<<g, 256, 0, stream>>>(q_act, kp, vb, Opart, ml);
    combine_kernel<<<LL * CC / 256, 256, 0, stream>>>(Opart, ml, att, stats);
    dim3 go(CC, 4);
    out_stats<<<go, 256, 0, stream>>>(att, Wo, bo, y, stats);
    out_final<<<go, 256, 0, stream>>>(y, stats, out);
}